// Round 6
// baseline (139.790 us; speedup 1.0000x reference)
//
#include <hip/hip_runtime.h>
#include <math.h>

// Problem constants (B,S,D,V,C) = (32, 2048, 512, 32000, 2)
#define BB   32
#define SS   2048
#define DD   512
#define VV   32000
#define JT   36              // 32 q-rows + w0 + w1 + 2 zero rows
#define QPAD 516             // q LDS row stride in floats (512 + 4)
#define GCH  8               // gather token-chunks per batch

// ---------------------------------------------------------------------------
// Pass 0: QT[36][512] (j-major): row j<32 = emb[tokens[j,0]], 32/33 = cls_w,
// 34/35 = zero. One block per j-row, 128 threads x float4.
// ---------------------------------------------------------------------------
__global__ __launch_bounds__(128) void build_qt(
    const int* __restrict__ tokens, const float* __restrict__ emb,
    const float* __restrict__ cls_w, float* __restrict__ QT)
{
    const int j   = blockIdx.x;    // 0..35
    const int tid = threadIdx.x;   // 128 threads * float4 = 512 floats
    float4 v = make_float4(0.f, 0.f, 0.f, 0.f);
    if (j < 32) {
        const int tok = tokens[(size_t)j * SS];
        v = ((const float4*)(emb + (size_t)tok * DD))[tid];
    } else if (j < 34) {
        v = ((const float4*)(cls_w + (size_t)(j - 32) * DD))[tid];
    }
    ((float4*)QT)[j * (DD / 4) + tid] = v;
}

// ---------------------------------------------------------------------------
// Pass A: St[v][j] = sum_d emb[v][d] * QT[j][d]
// Skinny GEMM, register-blocked. Lane = (ks = l&7, jg = (l>>3)&3, rg = l>>5):
// thread owns 8 rows x 9 j x 64 dims (ks-th K-segment), acc[72] in VGPRs.
//   - per 4-dim chunk: 9 ds_read_b128 (q) feed 288 FMAs  -> VALU-bound
//     (fixes r5's 36-b128/chunk LDS-pipe flood: LDS/CU 864 < VALU/SIMD 1152)
//   - K summed IN-WAVE: 3-step shfl_xor butterfly over the 8 ks lanes
//     -> St stays one 4.6 MB plane, no multi-plane Sh round-trip.
//   - wave = 16 rows x full K -> 2000 waves / 500 blocks (occupancy kept).
// q panel [36][QPAD] staged once per block with an XOR column swizzle
// (phys_c4 = c4 ^ ((c4>>4)&7), i.e. ^ks) applied on BOTH write and read
// (rule #21) so the 32 distinct broadcast addrs land <=2-way on banks (free).
// ---------------------------------------------------------------------------
__global__ __launch_bounds__(256, 2) void score_pass(
    const float* __restrict__ emb, const float* __restrict__ QT,
    float* __restrict__ St)
{
    const int bx  = blockIdx.x;          // 0..499
    const int tid = threadIdx.x;
    const int w   = tid >> 6;            // wave 0..3
    const int l   = tid & 63;
    const int ks  = l & 7;               // K-segment (64 dims)
    const int jg  = (l >> 3) & 3;        // j-group (9 j's)
    const int rg  = l >> 5;              // row-group (8 rows)

    __shared__ float qs[JT * QPAD];      // 74.3 KB -> 2 blocks/CU

    // ---- stage QT[36][512] -> qs, f4-column swizzled (36*128 = 4608 f4)
#pragma unroll
    for (int it = 0; it < 18; ++it) {
        const int idx = it * 256 + tid;
        const int r   = idx >> 7, c4 = idx & 127;
        const int p4  = c4 ^ ((c4 >> 4) & 7);          // ^ks swizzle
        *(float4*)&qs[r * QPAD + p4 * 4] = ((const float4*)QT)[r * 128 + c4];
    }
    __syncthreads();

    const int row0 = bx * 64 + w * 16 + rg * 8;        // first owned row
    const float* xb = emb + (size_t)row0 * DD + ks * 64;

    float acc[72];                                     // [rr][jj] = acc[rr*9+jj]
#pragma unroll
    for (int k = 0; k < 72; ++k) acc[k] = 0.f;

    float4 xc[8], xn[8];
#pragma unroll
    for (int rr = 0; rr < 8; ++rr)
        xc[rr] = *(const float4*)(xb + rr * DD);

    for (int c = 0; c < 16; ++c) {                     // 16 chunks of 4 dims
        if (c + 1 < 16) {
#pragma unroll
            for (int rr = 0; rr < 8; ++rr)
                xn[rr] = *(const float4*)(xb + rr * DD + (c + 1) * 4);
        }

        const int pc4 = (ks * 16 + c) ^ ks;            // swizzled phys f4-col
#pragma unroll
        for (int jj = 0; jj < 9; ++jj) {
            const float4 q = *(const float4*)&qs[(jg * 9 + jj) * QPAD + pc4 * 4];
#pragma unroll
            for (int rr = 0; rr < 8; ++rr) {
                float a = acc[rr * 9 + jj];
                a = fmaf(xc[rr].x, q.x, a);
                a = fmaf(xc[rr].y, q.y, a);
                a = fmaf(xc[rr].z, q.z, a);
                a = fmaf(xc[rr].w, q.w, a);
                acc[rr * 9 + jj] = a;
            }
        }

        if (c + 1 < 16) {
#pragma unroll
            for (int rr = 0; rr < 8; ++rr) xc[rr] = xn[rr];
        }
    }

    // ---- in-wave K-reduction: butterfly over ks (lane bits 0..2)
#pragma unroll
    for (int off = 1; off < 8; off <<= 1)
#pragma unroll
        for (int k = 0; k < 72; ++k)
            acc[k] += __shfl_xor(acc[k], off);

    // ---- ks==0 lanes hold the full-K result for their 8 rows x 9 j
    if (ks == 0) {
#pragma unroll
        for (int rr = 0; rr < 8; ++rr) {
            float* dst = St + (size_t)(row0 + rr) * JT + jg * 9;
#pragma unroll
            for (int jj = 0; jj < 9; ++jj) dst[jj] = acc[rr * 9 + jj];
        }
    }
}

// ---------------------------------------------------------------------------
// Pass B: per (batch, 256-token chunk): St is 4.6 MB (L2-resident). Two loads
// per token: s = St[tok][b], (u,v) = St[tok][32..33]; exp-sum -> one partial.
// ---------------------------------------------------------------------------
__global__ __launch_bounds__(256) void gather_pass(
    const int* __restrict__ tokens, const float* __restrict__ St,
    float4* __restrict__ part)
{
    const int b     = blockIdx.x;
    const int chunk = blockIdx.y;
    const int tid   = threadIdx.x;

    const int tok = tokens[(size_t)b * SS + chunk * 256 + tid];
    const float* p = St + (size_t)tok * JT;

    const float s  = p[b];                       // q_b . x_t (full K)
    const float2 uv = *(const float2*)(p + 32);  // w0.x_t, w1.x_t
    const float pe = __expf(s);                  // |s| <~ 0.5, no max needed
    float L = pe, d0 = pe * uv.x, d1 = pe * uv.y;

#pragma unroll
    for (int off = 32; off > 0; off >>= 1) {
        L  += __shfl_xor(L,  off);
        d0 += __shfl_xor(d0, off);
        d1 += __shfl_xor(d1, off);
    }

    __shared__ float sL[4], s0[4], s1[4];
    const int wave = tid >> 6, lane = tid & 63;
    if (lane == 0) { sL[wave] = L; s0[wave] = d0; s1[wave] = d1; }
    __syncthreads();
    if (tid == 0) {
        part[(size_t)b * GCH + chunk] =
            make_float4(sL[0] + sL[1] + sL[2] + sL[3],
                        s0[0] + s0[1] + s0[2] + s0[3],
                        s1[0] + s1[1] + s1[2] + s1[3], 0.f);
    }
}

// ---------------------------------------------------------------------------
// Pass C: fold the 8 chunk-partials per batch; emit logits. One tiny block.
// ---------------------------------------------------------------------------
__global__ __launch_bounds__(256) void final_merge(
    const float4* __restrict__ part, const float* __restrict__ cls_b,
    float* __restrict__ out)
{
    const int tid = threadIdx.x;       // 256 = 32 b x 8 chunks
    const int b = tid >> 3, i = tid & 7;
    const float4 v = part[b * GCH + i];
    float L = v.x, d0 = v.y, d1 = v.z;
#pragma unroll
    for (int off = 4; off > 0; off >>= 1) {   // 8-lane groups, wave-aligned
        L  += __shfl_xor(L,  off);
        d0 += __shfl_xor(d0, off);
        d1 += __shfl_xor(d1, off);
    }
    if (i == 0) {
        const float inv = 1.0f / L;
        out[b * 2 + 0] = d0 * inv + cls_b[0];
        out[b * 2 + 1] = d1 * inv + cls_b[1];
    }
}

// ---------------------------------------------------------------------------
extern "C" void kernel_launch(void* const* d_in, const int* in_sizes, int n_in,
                              void* d_out, int out_size, void* d_ws, size_t ws_size,
                              hipStream_t stream)
{
    const int*   tokens = (const int*)  d_in[0];   // (32, 2048)
    const float* emb    = (const float*)d_in[1];   // (32000, 512)
    const float* cls_w  = (const float*)d_in[2];   // (2, 512)
    const float* cls_b  = (const float*)d_in[3];   // (2,)
    float*       out    = (float*)d_out;           // (32, 2)

    // Workspace:
    //   QT[36][512]         =  73.7 KB  (j-major)
    //   St[32000][36]       =   4.6 MB  (single plane, written once)
    //   part[32][8] float4  =   2.0 KB
    float*  QT   = (float*)d_ws;
    float*  St   = QT + (size_t)JT * DD;
    float4* part = (float4*)(St + (size_t)VV * JT);

    build_qt   <<<JT, 128, 0, stream>>>(tokens, emb, cls_w, QT);
    score_pass <<<VV / 64, 256, 0, stream>>>(emb, QT, St);
    gather_pass<<<dim3(BB, GCH), 256, 0, stream>>>(tokens, St, part);
    final_merge<<<1, 256, 0, stream>>>(part, cls_b, out);
}